// Round 1
// baseline (204.347 us; speedup 1.0000x reference)
//
#include <hip/hip_runtime.h>
#include <math.h>

#define O_CH 32
#define I_CH 3
#define IH 512
#define IW 512
#define OH 510
#define OW 510
#define N_IMG 16

#define TW 128          // output tile width
#define TH 8            // output tile height
#define PX 4            // output px per thread (x)
#define TIW (TW + 2)    // 130 input cols needed
#define TIWP 132        // padded LDS row stride (keeps float4 alignment, breaks pow2)
#define TIH (TH + 2)    // 10 input rows needed

__global__ __launch_bounds__(256) void gabor_weights_kernel(
    const float* __restrict__ freq, const float* __restrict__ theta,
    const float* __restrict__ psi, const float* __restrict__ sigma,
    float* __restrict__ w) {
  int idx = blockIdx.x * 256 + threadIdx.x;
  if (idx >= O_CH * I_CH * 9) return;
  int kw = idx % 3;
  int kh = (idx / 3) % 3;
  int oc = idx / 9;  // flat (o*3 + c) index into the (O,I) parameter arrays
  // linspace(-ceil(3/2)+1, ceil(3/2), 3) = {-1, 0.5, 2}
  float x = (kw == 0) ? -1.0f : (kw == 1 ? 0.5f : 2.0f);
  float y = (kh == 0) ? -1.0f : (kh == 1 ? 0.5f : 2.0f);
  float th = theta[oc], f = freq[oc], p = psi[oc], s = sigma[oc];
  float ct = cosf(th), st = sinf(th);
  float rotx = x * ct + y * st;
  float roty = -x * st + y * ct;
  float se = s + 0.001f;
  float g = expf(-0.5f * (rotx * rotx + roty * roty) / (se * se));
  g *= cosf(f * rotx + p);
  g /= (2.0f * 3.14f * s * s);   // reference uses PI = 3.14 exactly
  w[idx] = g;
}

__global__ __launch_bounds__(256) void gabor_conv_kernel(
    const float* __restrict__ in, const float* __restrict__ wg,
    float* __restrict__ out) {
  __shared__ float sIn[I_CH][TIH][TIWP];
  __shared__ float sW[O_CH][28];

  const int tid = threadIdx.x;
  const int n = blockIdx.z;
  const int ty0 = blockIdx.y * TH;
  const int tx0 = blockIdx.x * TW;

  const float* inN = in + (size_t)n * I_CH * IH * IW;

  // Stage input tile (halo'd, edge-clamped; clamped elems only feed OOB outputs)
  for (int i = tid; i < I_CH * TIH * TIW; i += 256) {
    int col = i % TIW;
    int t = i / TIW;
    int row = t % TIH;
    int c = t / TIH;
    int gr = ty0 + row; if (gr > IH - 1) gr = IH - 1;
    int gc = tx0 + col; if (gc > IW - 1) gc = IW - 1;
    sIn[c][row][col] = inN[(c * IH + gr) * IW + gc];
  }
  // Stage weights [o][27] padded to stride 28 (112 B, 16B-aligned rows)
  for (int i = tid; i < O_CH * 27; i += 256) {
    sW[i / 27][i % 27] = wg[i];
  }
  __syncthreads();

  const int txi = tid & 31;   // 32 threads across x
  const int tyi = tid >> 5;   // 8 rows
  const int lx = txi * PX;
  const int oy = ty0 + tyi;
  const int ox = tx0 + lx;

  // Input window for 4 output px: 3 ch x 3 rows x 6 cols, in registers
  float r[I_CH][3][6];
#pragma unroll
  for (int c = 0; c < I_CH; ++c) {
#pragma unroll
    for (int kh = 0; kh < 3; ++kh) {
      float4 v = *(const float4*)&sIn[c][tyi + kh][lx];       // 16B-aligned
      float2 u = *(const float2*)&sIn[c][tyi + kh][lx + 4];   // 8B-aligned
      r[c][kh][0] = v.x; r[c][kh][1] = v.y;
      r[c][kh][2] = v.z; r[c][kh][3] = v.w;
      r[c][kh][4] = u.x; r[c][kh][5] = u.y;
    }
  }

  const bool rowOK = (oy < OH);
  float* outN = out + (size_t)n * O_CH * OH * OW;

  for (int o = 0; o < O_CH; ++o) {
    // 27 weights for this o, broadcast ds_read_b128 x7 (conflict-free)
    float wv[28];
#pragma unroll
    for (int k = 0; k < 7; ++k) {
      float4 t4 = *(const float4*)&sW[o][k * 4];
      wv[k * 4 + 0] = t4.x; wv[k * 4 + 1] = t4.y;
      wv[k * 4 + 2] = t4.z; wv[k * 4 + 3] = t4.w;
    }
    float a0 = 0.f, a1 = 0.f, a2 = 0.f, a3 = 0.f;
#pragma unroll
    for (int c = 0; c < I_CH; ++c) {
#pragma unroll
      for (int kh = 0; kh < 3; ++kh) {
#pragma unroll
        for (int kw = 0; kw < 3; ++kw) {
          float w = wv[c * 9 + kh * 3 + kw];
          a0 = fmaf(r[c][kh][kw + 0], w, a0);
          a1 = fmaf(r[c][kh][kw + 1], w, a1);
          a2 = fmaf(r[c][kh][kw + 2], w, a2);
          a3 = fmaf(r[c][kh][kw + 3], w, a3);
        }
      }
    }
    if (rowOK) {
      size_t ob = ((size_t)o * OH + oy) * OW + ox;
      if (ox + PX <= OW) {
        // base index is always even -> 8B-aligned float2 stores
        *(float2*)&outN[ob] = make_float2(a0, a1);
        *(float2*)&outN[ob + 2] = make_float2(a2, a3);
      } else {
        if (ox + 0 < OW) outN[ob + 0] = a0;
        if (ox + 1 < OW) outN[ob + 1] = a1;
        if (ox + 2 < OW) outN[ob + 2] = a2;
        if (ox + 3 < OW) outN[ob + 3] = a3;
      }
    }
  }
}

extern "C" void kernel_launch(void* const* d_in, const int* in_sizes, int n_in,
                              void* d_out, int out_size, void* d_ws, size_t ws_size,
                              hipStream_t stream) {
  const float* img   = (const float*)d_in[0];
  const float* freq  = (const float*)d_in[1];
  const float* theta = (const float*)d_in[2];
  const float* psi   = (const float*)d_in[3];
  const float* sigma = (const float*)d_in[4];
  float* outp = (float*)d_out;
  float* wg = (float*)d_ws;  // 864 floats of scratch for the Gabor weights

  gabor_weights_kernel<<<dim3(4), dim3(256), 0, stream>>>(freq, theta, psi, sigma, wg);

  dim3 grid((OW + TW - 1) / TW, (OH + TH - 1) / TH, N_IMG);  // 4 x 64 x 16
  gabor_conv_kernel<<<grid, dim3(256), 0, stream>>>(img, wg, outp);
}